// Round 5
// baseline (490.747 us; speedup 1.0000x reference)
//
#include <hip/hip_runtime.h>
#include <math.h>

#define SQ 96            // H == W == 96
#define CQ 256
#define HWQ 9216         // 96*96
#define PIXQ 73728       // 8*9216

typedef __attribute__((ext_vector_type(8))) __bf16 bf16x8;
typedef __attribute__((ext_vector_type(4))) float f32x4;

union FragU { uint4 u; bf16x8 b; };

// round-to-nearest-even fp32 -> bf16 (as u16 in low bits)
__device__ inline uint32_t bf16_rne_u(float f) {
  uint32_t u = __float_as_uint(f);
  return (u + 0x7FFFu + ((u >> 16) & 1u)) >> 16;
}
// split fp32 into hi (RNE bf16) + lo (truncated bf16 of residual), packed u32
__device__ inline uint32_t pack_split(float f) {
  uint32_t hi = bf16_rne_u(f);
  float rem = f - __uint_as_float(hi << 16);
  uint32_t lo = __float_as_uint(rem) >> 16;
  return hi | (lo << 16);
}

__device__ inline void async_copy16(const void* g, void* l) {
  __builtin_amdgcn_global_load_lds(
      (const __attribute__((address_space(1))) void*)g,
      (__attribute__((address_space(3))) void*)l, 16, 0, 0);
}

// ---------------------------------------------------------------------------
// Build Wbig (512x256) split planes: rows 0..255 = G = Wq^T Wk (fp32 GEMM),
// rows 256..511 = Wv.  w layout: w[o][c], o<256: Wq rows, 256..511: Wk,
// 512..767: Wv.  G[n][j] = sum_o Wq[o][n]*Wk[o][j].
// ---------------------------------------------------------------------------
__global__ __launch_bounds__(256) void build_wbig(
    const float* __restrict__ w, ushort* __restrict__ wbhi,
    ushort* __restrict__ wblo) {
  const int n = blockIdx.x;        // 0..511
  const int j = threadIdx.x;       // 0..255
  float val;
  if (n < 256) {
    float acc = 0.0f;
#pragma unroll 4
    for (int o = 0; o < 256; ++o)
      acc = fmaf(w[o * 256 + n], w[(256 + o) * 256 + j], acc);
    val = acc;
  } else {
    val = w[(256 + n) * 256 + j];  // Wv row (n-256): w[(512+n-256)*256+j]
  }
  uint32_t p = pack_split(val);
  wbhi[n * 256 + j] = (ushort)p;
  wblo[n * 256 + j] = (ushort)(p >> 16);
}

// ---------------------------------------------------------------------------
// c2[c] = sum_o Wk[o][c]*bq[o]   (Sh column-offset vector)
// c3[c] = sum_o Wq[o][c]*bk[o]   (Sw column-offset vector)
// ---------------------------------------------------------------------------
__global__ __launch_bounds__(256) void build_c2c3(
    const float* __restrict__ w, const float* __restrict__ bias,
    float* __restrict__ c2, float* __restrict__ c3) {
  const int c = threadIdx.x;
  if (blockIdx.x == 0) {
    float acc = 0.0f;
#pragma unroll 4
    for (int o = 0; o < 256; ++o)
      acc = fmaf(w[(256 + o) * 256 + c], bias[o], acc);
    c2[c] = acc;
  } else {
    float acc = 0.0f;
#pragma unroll 4
    for (int o = 0; o < 256; ++o)
      acc = fmaf(w[o * 256 + c], bias[256 + o], acc);
    c3[c] = acc;
  }
}

// ---------------------------------------------------------------------------
// Pre-split x into hi/lo bf16 planes (in d_ws).  x-planes keep x's native
// w-major pixel order: pix = b*9216 + w*96 + h.
// ---------------------------------------------------------------------------
__global__ __launch_bounds__(256) void split_x(
    const float* __restrict__ x, ushort* __restrict__ xhi,
    ushort* __restrict__ xlo) {
  size_t i = ((size_t)blockIdx.x * 256 + threadIdx.x) * 4;
  float4 v = *(const float4*)(x + i);
  ushort4 h, l;
  uint32_t p;
  p = pack_split(v.x); h.x = (ushort)p; l.x = (ushort)(p >> 16);
  p = pack_split(v.y); h.y = (ushort)p; l.y = (ushort)(p >> 16);
  p = pack_split(v.z); h.z = (ushort)p; l.z = (ushort)(p >> 16);
  p = pack_split(v.w); h.w = (ushort)p; l.w = (ushort)(p >> 16);
  *(ushort4*)(xhi + i) = h;
  *(ushort4*)(xlo + i) = l;
}

// ---------------------------------------------------------------------------
// tq[b,i] = c2 . (sum_w x[b,w,i,:])   (Sh col offsets, i = h2)
// tk[b,i] = c3 . (sum_h x[b,i,h,:])   (Sw col offsets, i = w2)
// x layout: x[((b*96+w)*96+h)*256+c]
// ---------------------------------------------------------------------------
__global__ __launch_bounds__(256) void build_tqtk(
    const float* __restrict__ x, const float* __restrict__ c2,
    const float* __restrict__ c3, float* __restrict__ tq,
    float* __restrict__ tk) {
  __shared__ float red[256];
  const int i = blockIdx.x;    // 0..95
  const int b = blockIdx.y;    // 0..7
  const int c = threadIdx.x;
  float accq = 0.0f, acck = 0.0f;
  for (int s = 0; s < 96; ++s) {
    accq += x[(((size_t)b * SQ + s) * SQ + i) * CQ + c];   // sum over w
    acck += x[(((size_t)b * SQ + i) * SQ + s) * CQ + c];   // sum over h
  }
  red[c] = accq * c2[c];
  __syncthreads();
  for (int s = 128; s > 0; s >>= 1) {
    if (c < s) red[c] += red[c + s];
    __syncthreads();
  }
  if (c == 0) tq[b * SQ + i] = red[0];
  __syncthreads();
  red[c] = acck * c3[c];
  __syncthreads();
  for (int s = 128; s > 0; s >>= 1) {
    if (c < s) red[c] += red[c + s];
    __syncthreads();
  }
  if (c == 0) tk[b * SQ + i] = red[0];
}

// ---------------------------------------------------------------------------
// Initialize Sh[b,h1,h2] = tq[b,h2]; Sw[b,w1,w2] = tk[b,w2]  (pre-atomic).
// ---------------------------------------------------------------------------
__global__ __launch_bounds__(128) void init_scores(
    const float* __restrict__ tq, const float* __restrict__ tk,
    float* __restrict__ Sh, float* __restrict__ Sw) {
  const int id = blockIdx.x;          // 0..1535
  const int t = threadIdx.x;
  if (t >= 96) return;
  if (id < 768) {
    int b = id / 96, rr = id - b * 96;
    Sh[((size_t)(b * SQ + rr)) * SQ + t] = tq[b * SQ + t];
  } else {
    int id2 = id - 768;
    int b = id2 / 96, rr = id2 - b * 96;
    Sw[((size_t)(b * SQ + rr)) * SQ + t] = tk[b * SQ + t];
  }
}

// ---------------------------------------------------------------------------
// y&v GEMM via 3-product split-bf16 MFMA.  M=73728 (p=(b,w,h)), N=512, K=256.
// B = Wbig (rows 0..255 = G -> y;  256..511 = Wv -> v).
// Block 128x128, 4 waves (2x2) of 64x64.  LDS: 4 planes (xhi,xlo,wbhi,wblo),
// rows of 32 bf16 (64 B), 16B chunks XOR-swizzled (conflict-free, DMA-staged).
// Outputs: y split planes (yhi/ylo), v bf16 (vb); pixel stored h-major.
// ---------------------------------------------------------------------------
__global__ __launch_bounds__(256) void yv_gemm_mfma(
    const ushort* __restrict__ xhi, const ushort* __restrict__ xlo,
    const ushort* __restrict__ wbhi, const ushort* __restrict__ wblo,
    const float* __restrict__ bias, ushort* __restrict__ yhi,
    ushort* __restrict__ ylo, ushort* __restrict__ vb) {
  __shared__ ushort lds[4][128][32];    // 32 KB
  const int tid = threadIdx.x;
  const int lane = tid & 63;
  const int wid = tid >> 6;
  const int wm = wid >> 1, wn = wid & 1;
  const int lr = lane & 15, quad = lane >> 4;
  const int m0 = blockIdx.x * 128, n0 = blockIdx.y * 128;

  const ushort* gplane = (wid == 0) ? xhi : (wid == 1) ? xlo
                       : (wid == 2) ? wbhi : wblo;
  const int rowbase = (wid < 2) ? m0 : n0;
  const int srow = lane >> 2;                                  // 0..15
  const int lc = (lane & 3) ^ ((lane >> 2) & 3) ^ ((lane >> 4) & 3);
  const int swz = (lr & 3) ^ ((lr >> 2) & 3);
  const int ca = ((quad ^ swz) * 8);

  f32x4 acc[4][4] = {};

  for (int k0 = 0; k0 < 256; k0 += 32) {
#pragma unroll
    for (int i = 0; i < 8; ++i) {
      int row = i * 16 + srow;
      const ushort* g = gplane + (size_t)(rowbase + row) * 256 + k0 + lc * 8;
      async_copy16(g, &lds[wid][i * 16][0]);
    }
    __syncthreads();

    FragU ah[4], al[4], bh[4], bl[4];
#pragma unroll
    for (int t = 0; t < 4; ++t) {
      int ra = wm * 64 + t * 16 + lr;
      int rb = wn * 64 + t * 16 + lr;
      ah[t].u = *(const uint4*)&lds[0][ra][ca];
      al[t].u = *(const uint4*)&lds[1][ra][ca];
      bh[t].u = *(const uint4*)&lds[2][rb][ca];
      bl[t].u = *(const uint4*)&lds[3][rb][ca];
    }
#pragma unroll
    for (int i = 0; i < 4; ++i)
#pragma unroll
      for (int j = 0; j < 4; ++j) {
        acc[i][j] = __builtin_amdgcn_mfma_f32_16x16x32_bf16(ah[i].b, bh[j].b, acc[i][j], 0, 0, 0);
        acc[i][j] = __builtin_amdgcn_mfma_f32_16x16x32_bf16(ah[i].b, bl[j].b, acc[i][j], 0, 0, 0);
        acc[i][j] = __builtin_amdgcn_mfma_f32_16x16x32_bf16(al[i].b, bh[j].b, acc[i][j], 0, 0, 0);
      }
    __syncthreads();
  }

  // epilogue: C[row=(quad*4+r)][col=lr] per 16x16 tile
#pragma unroll
  for (int i = 0; i < 4; ++i) {
    const int growb = m0 + wm * 64 + i * 16 + quad * 4;
#pragma unroll
    for (int r = 0; r < 4; ++r) {
      int p = growb + r;                 // input pixel order (b, w, h)
      int b = p / HWQ;
      int rem = p - b * HWQ;
      int ww = rem / SQ;
      int hh = rem - ww * SQ;
      size_t opix = (size_t)b * HWQ + (size_t)hh * SQ + ww;   // h-major
#pragma unroll
      for (int j = 0; j < 4; ++j) {
        int o = n0 + wn * 64 + j * 16 + lr;
        if (o < 256) {                   // y plane (no bias)
          uint32_t pk = pack_split(acc[i][j][r]);
          yhi[opix * 256 + o] = (ushort)pk;
          ylo[opix * 256 + o] = (ushort)(pk >> 16);
        } else {                         // v plane, bias bv = bias[512 + (o-256)]
          float val = acc[i][j][r] + bias[256 + o];
          vb[opix * 256 + (o - 256)] = (ushort)bf16_rne_u(val);
        }
      }
    }
  }
}

// ---------------------------------------------------------------------------
// Attention scores, 3-product split MFMA, planes + swizzled DMA staging.
// which=0: Sh[b,h1,h2] += sum_{w,c} x(h1,w,c)*y(h2,w,c)   X=x, Y=y
// which=1: Sw[b,w1,w2] += sum_{h,c} y(w1,h,c)*x(w2,h,c)   X=y, Y=x
// LAYOUTS: x-planes are w-major (pix = b*9216 + w*96 + h);
//          y-planes are h-major (pix = b*9216 + h*96 + w).
// Working through all 4 (which, operand) cases, the X operand (waves 0,1)
// always stages pix = pbase + kout*96 + row, and the Y operand (waves 2,3)
// always stages pix = pbase + row*96 + kout.
// ---------------------------------------------------------------------------
__global__ __launch_bounds__(256) void attn_scores_mfma(
    const ushort* __restrict__ xhi, const ushort* __restrict__ xlo,
    const ushort* __restrict__ yhi, const ushort* __restrict__ ylo,
    float* __restrict__ Sh, float* __restrict__ Sw) {
  __shared__ ushort lds[4][96][32];   // Xhi, Xlo, Yhi, Ylo (24 KB)
  const int tid = threadIdx.x;
  const int lane = tid & 63;
  const int wid = tid >> 6;
  const int wm = wid >> 1, wn = wid & 1;
  const int lr = lane & 15, quad = lane >> 4;
  const int chunk = blockIdx.x;      // 0..31 (3 kouts each)
  const int b = blockIdx.y;          // 0..7
  const int which = blockIdx.z;      // 0=Sh, 1=Sw
  const size_t pbase = (size_t)b * HWQ;

  const ushort* gp;
  if (which == 0)
    gp = (wid == 0) ? xhi : (wid == 1) ? xlo : (wid == 2) ? yhi : ylo;
  else
    gp = (wid == 0) ? yhi : (wid == 1) ? ylo : (wid == 2) ? xhi : xlo;
  const bool xop = (wid < 2);        // staging the X (A-side) operand?

  const int srow = lane >> 2;
  const int lc = (lane & 3) ^ ((lane >> 2) & 3) ^ ((lane >> 4) & 3);
  const int swz = (lr & 3) ^ ((lr >> 2) & 3);
  const int ca = ((quad ^ swz) * 8);

  f32x4 acc[3][3] = {};

  for (int it = 0; it < 24; ++it) {
    int kout = chunk * 3 + (it >> 3);     // w (Sh) or h (Sw)
    int c0 = (it & 7) * 32;
#pragma unroll
    for (int i = 0; i < 6; ++i) {
      int row = i * 16 + srow;            // 0..95
      size_t pix = xop ? (pbase + (size_t)kout * SQ + row)
                       : (pbase + (size_t)row * SQ + kout);
      async_copy16(gp + pix * 256 + c0 + lc * 8, &lds[wid][i * 16][0]);
    }
    __syncthreads();

    FragU xh[3], xl[3], yh[3], yl[3];
#pragma unroll
    for (int t = 0; t < 3; ++t) {
      int rx = wm * 48 + t * 16 + lr;
      int ry = wn * 48 + t * 16 + lr;
      xh[t].u = *(const uint4*)&lds[0][rx][ca];
      xl[t].u = *(const uint4*)&lds[1][rx][ca];
      yh[t].u = *(const uint4*)&lds[2][ry][ca];
      yl[t].u = *(const uint4*)&lds[3][ry][ca];
    }
#pragma unroll
    for (int i = 0; i < 3; ++i)
#pragma unroll
      for (int j = 0; j < 3; ++j) {
        acc[i][j] = __builtin_amdgcn_mfma_f32_16x16x32_bf16(xh[i].b, yh[j].b, acc[i][j], 0, 0, 0);
        acc[i][j] = __builtin_amdgcn_mfma_f32_16x16x32_bf16(xh[i].b, yl[j].b, acc[i][j], 0, 0, 0);
        acc[i][j] = __builtin_amdgcn_mfma_f32_16x16x32_bf16(xl[i].b, yh[j].b, acc[i][j], 0, 0, 0);
      }
    __syncthreads();
  }
  float* S = which ? Sw : Sh;
#pragma unroll
  for (int i = 0; i < 3; ++i)
#pragma unroll
    for (int r = 0; r < 4; ++r)
#pragma unroll
      for (int j = 0; j < 3; ++j) {
        int row = wm * 48 + i * 16 + quad * 4 + r;
        int col = wn * 48 + j * 16 + lr;
        atomicAdd(S + ((size_t)b * SQ + row) * SQ + col, acc[i][j][r]);
      }
}

// ---------------------------------------------------------------------------
// Softmax over last dim (96); emits bf16 probabilities.
// ---------------------------------------------------------------------------
__global__ __launch_bounds__(256) void softmax_p(
    const float* __restrict__ Sh, const float* __restrict__ Sw,
    ushort* __restrict__ Pms, ushort* __restrict__ Pma) {
  const int tid = threadIdx.x;
  const int lane = tid & 63;
  const int row = blockIdx.x * 4 + (tid >> 6);
  const float* p = (row < 768) ? (Sh + (size_t)row * SQ)
                               : (Sw + (size_t)(row - 768) * SQ);
  ushort* q = (row < 768) ? (Pms + (size_t)row * SQ)
                          : (Pma + (size_t)(row - 768) * SQ);
  float v0 = p[lane];
  float v1 = (lane < 32) ? p[64 + lane] : -3.0e38f;
  float m = fmaxf(v0, v1);
#pragma unroll
  for (int off = 32; off > 0; off >>= 1) m = fmaxf(m, __shfl_xor(m, off));
  float e0 = __expf(v0 - m);
  float e1 = (lane < 32) ? __expf(v1 - m) : 0.0f;
  float s = e0 + e1;
#pragma unroll
  for (int off = 32; off > 0; off >>= 1) s += __shfl_xor(s, off);
  float inv = 1.0f / s;
  q[lane] = (ushort)bf16_rne_u(e0 * inv);
  if (lane < 32) q[64 + lane] = (ushort)bf16_rne_u(e1 * inv);
}

// ---------------------------------------------------------------------------
// Apply attention via single-bf16 MFMA.  out: ((b*96 + w)*96 + h)*256 + c
// which=0 (block b, xi=w): O[h][c]  = sum_h2 Pms[b,h,h2] * V[b,h2,xi,c]
// which=1 (block b, xi=h): O[w][c] += sum_w2 Pma[b,w,w2] * V[b,xi,w2,c]
// (vb is h-major: V[b,h,w,c] at ((b*9216 + h*96 + w)*256 + c))
// ---------------------------------------------------------------------------
__global__ __launch_bounds__(256) void attn_apply_mfma(
    const ushort* __restrict__ vb, const ushort* __restrict__ P,
    float* __restrict__ out, const int which) {
  __shared__ ushort Vt[256 * 40];      // [c][k] stride 40 (80B, 16B-mult)
  const int tid = threadIdx.x;
  const int lane = tid & 63;
  const int wid = tid >> 6;
  const int wm = wid >> 1, wn = wid & 1;
  const int lr = lane & 15, quad = lane >> 4;
  const int xi = blockIdx.x;           // w (which=0) or h (which=1)
  const int b = blockIdx.y;

  f32x4 acc[3][8] = {};

  for (int k0 = 0; k0 < 96; k0 += 32) {
#pragma unroll
    for (int j = 0; j < 8; ++j) {
      int bi = j * 256 + tid;          // 0..2047
      int c2 = bi & 127;               // c-pair index
      int k2 = bi >> 7;                // k-pair index 0..15
      int k = k0 + k2 * 2;
      int c = c2 * 2;
      size_t r0, r1;
      if (which == 0) {
        r0 = ((size_t)b * HWQ + (size_t)k * SQ + xi) * CQ + c;
        r1 = r0 + (size_t)SQ * CQ;
      } else {
        r0 = ((size_t)b * HWQ + (size_t)xi * SQ + k) * CQ + c;
        r1 = r0 + CQ;
      }
      uint32_t a0 = *(const uint32_t*)(vb + r0);
      uint32_t a1 = *(const uint32_t*)(vb + r1);
      uint32_t w0 = (a0 & 0xFFFFu) | (a1 << 16);
      uint32_t w1 = (a0 >> 16) | (a1 & 0xFFFF0000u);
      *(uint32_t*)&Vt[c * 40 + k2 * 2] = w0;
      *(uint32_t*)&Vt[(c + 1) * 40 + k2 * 2] = w1;
    }
    __syncthreads();
    FragU a[3];
#pragma unroll
    for (int t = 0; t < 3; ++t) {
      int row = wm * 48 + t * 16 + lr;
      const ushort* ps = P + ((size_t)b * SQ + row) * SQ + k0 + quad * 8;
      a[t].u = *(const uint4*)ps;
    }
#pragma unroll
    for (int j = 0; j < 8; ++j) {
      int cb = wn * 128 + j * 16 + lr;
      FragU bf;
      bf.u = *(const uint4*)&Vt[cb * 40 + quad * 8];
#pragma unroll
      for (int i = 0; i < 3; ++i)
        acc[i][j] = __builtin_amdgcn_mfma_f32_16x16x32_bf16(a[i].b, bf.b, acc[i][j], 0, 0, 0);
    }
    __syncthreads();
  }

#pragma unroll
  for (int i = 0; i < 3; ++i) {
#pragma unroll
    for (int r = 0; r < 4; ++r) {
      int mrow = wm * 48 + i * 16 + quad * 4 + r;
      size_t obase;
      if (which == 0) obase = (((size_t)b * SQ + xi) * SQ + mrow) * CQ;
      else            obase = (((size_t)b * SQ + mrow) * SQ + xi) * CQ;
#pragma unroll
      for (int j = 0; j < 8; ++j) {
        int c = wn * 128 + j * 16 + lr;
        if (which == 0) out[obase + c] = acc[i][j][r];
        else            out[obase + c] += acc[i][j][r];
      }
    }
  }
}

// ---------------------------------------------------------------------------
extern "C" void kernel_launch(void* const* d_in, const int* in_sizes, int n_in,
                              void* d_out, int out_size, void* d_ws,
                              size_t ws_size, hipStream_t stream) {
  const float* x = (const float*)d_in[0];      // (8,96,96,256) = (B,W,H,C)
  const float* w = (const float*)d_in[1];      // (768,256)
  const float* bias = (const float*)d_in[2];   // (768,)
  float* out = (float*)d_out;                  // (8,96,96,256) = (B,W,H,C)

  // workspace (~190 MB, all scratch in d_ws; d_out only written at the end)
  ushort* xhi = (ushort*)d_ws;                           // PIXQ*256
  ushort* xlo = xhi + (size_t)PIXQ * 256;
  ushort* yhi = xlo + (size_t)PIXQ * 256;
  ushort* ylo = yhi + (size_t)PIXQ * 256;
  ushort* vb  = ylo + (size_t)PIXQ * 256;
  float*  Sh  = (float*)(vb + (size_t)PIXQ * 256);       // 73728 f32
  float*  Sw  = Sh + PIXQ;
  ushort* Pms = (ushort*)(Sw + PIXQ);                    // 73728 ushort
  ushort* Pma = Pms + PIXQ;
  ushort* wbhi = Pma + PIXQ;                             // 512*256
  ushort* wblo = wbhi + 512 * 256;
  float*  c2  = (float*)(wblo + 512 * 256);              // 256 f32
  float*  c3  = c2 + 256;
  float*  tq  = c3 + 256;                                // 768 f32
  float*  tk  = tq + 768;

  build_wbig<<<dim3(512), 256, 0, stream>>>(w, wbhi, wblo);
  build_c2c3<<<dim3(2), 256, 0, stream>>>(w, bias, c2, c3);
  split_x<<<dim3(18432), 256, 0, stream>>>(x, xhi, xlo);
  build_tqtk<<<dim3(96, 8), 256, 0, stream>>>(x, c2, c3, tq, tk);
  init_scores<<<dim3(1536), 128, 0, stream>>>(tq, tk, Sh, Sw);
  yv_gemm_mfma<<<dim3(576, 4), 256, 0, stream>>>(xhi, xlo, wbhi, wblo, bias,
                                                 yhi, ylo, vb);
  attn_scores_mfma<<<dim3(32, 8, 2), 256, 0, stream>>>(xhi, xlo, yhi, ylo,
                                                       Sh, Sw);
  softmax_p<<<dim3(384), 256, 0, stream>>>(Sh, Sw, Pms, Pma);
  attn_apply_mfma<<<dim3(96, 8), 256, 0, stream>>>(vb, Pms, out, 0);
  attn_apply_mfma<<<dim3(96, 8), 256, 0, stream>>>(vb, Pma, out, 1);
}